// Round 1
// 735.510 us; speedup vs baseline: 1.0146x; 1.0146x over previous
//
#include <hip/hip_runtime.h>

#define BB  2
#define NN  512
#define DD  256
#define DHH 16

typedef __attribute__((ext_vector_type(8))) short short8;
typedef __attribute__((ext_vector_type(4))) float floatx4;

static __device__ __forceinline__ float bf2f(unsigned short u) {
    union { unsigned int i; float f; } v; v.i = ((unsigned int)u) << 16; return v.f;
}
static __device__ __forceinline__ unsigned short f2bf(float f) {
    union { float f; unsigned int i; } v; v.f = f;
    unsigned int r = v.i + 0x7FFFu + ((v.i >> 16) & 1u);   // RNE
    return (unsigned short)(r >> 16);
}

template<bool F32>
static __device__ __forceinline__ float ldin(const void* __restrict__ p, long i) {
    if (F32) return ((const float* __restrict__)p)[i];
    else     return bf2f(((const unsigned short* __restrict__)p)[i]);
}

// ---------------- K1: node projections + We repack + dtype self-detect -----
template<bool F32>
static __device__ __forceinline__ void proj_body(
    const void* __restrict__ x,
    const void* __restrict__ Wq, const void* __restrict__ bq,
    const void* __restrict__ Wk, const void* __restrict__ bk,
    const void* __restrict__ Wv, const void* __restrict__ bv,
    const void* __restrict__ Wni, const void* __restrict__ bni,
    const void* __restrict__ Wnj, const void* __restrict__ bnj,
    const void* __restrict__ We,
    float* __restrict__ proj, unsigned short* __restrict__ Bpack,
    float* __restrict__ xs)
{
    const int row = blockIdx.x;          // b*N + n
    const int t = threadIdx.x;           // 0..255
    xs[t] = ldin<F32>(x, (long)row * DD + t);
    __syncthreads();
    if (t < 80) {
        const int p = t >> 4, h = t & 15;
        const void* W; const void* bias;
        if (p == 0)      { W = Wq;  bias = bq;  }
        else if (p == 1) { W = Wk;  bias = bk;  }
        else if (p == 2) { W = Wv;  bias = bv;  }
        else if (p == 3) { W = Wni; bias = bni; }
        else             { W = Wnj; bias = bnj; }
        float s = ldin<F32>(bias, h);
        #pragma unroll 8
        for (int d = 0; d < DD; ++d) s += xs[d] * ldin<F32>(W, d * DHH + h);
        proj[(p * (BB * NN) + row) * DHH + h] = s;
    }
    if (blockIdx.x == 0 && t < 64) {
        #pragma unroll
        for (int kk = 0; kk < 8; ++kk)
            #pragma unroll
            for (int j = 0; j < 8; ++j) {
                const int widx = (kk * 32 + (t >> 4) * 8 + j) * DHH + (t & 15);
                unsigned short wv;
                if (F32) wv = f2bf(((const float*)We)[widx]);
                else     wv = ((const unsigned short*)We)[widx];
                Bpack[(kk * 64 + t) * 8 + j] = wv;
            }
    }
}

__global__ __launch_bounds__(256) void k_proj(
    const void* x, const void* Wq, const void* bq, const void* Wk, const void* bk,
    const void* Wv, const void* bv, const void* Wni, const void* bni,
    const void* Wnj, const void* bnj, const void* We,
    float* proj, unsigned short* Bpack, int* flag)
{
    __shared__ float xs[DD];
    __shared__ int sflag;
    const int t = threadIdx.x;
    // dtype detection, per-block (wave 0 only), replaces the k_detect launch.
    // bf16 buffer: every ushort is a sane-exponent bf16 of ~N(0,1) data.
    // fp32 buffer: even-index ushorts are low mantissa halves -> random exponents.
    if (t < 64) {
        const unsigned short u = ((const unsigned short*)x)[t * 2];
        const int ex = (u >> 7) & 0xFF;
        const int sane = (ex >= 115 && ex <= 131) ? 1 : 0;
        unsigned long long mball = __ballot(sane);
        if (t == 0) sflag = (__popcll(mball) < 32) ? 1 : 0;   // 1 = fp32, 0 = bf16
    }
    __syncthreads();
    const int f = sflag;
    if (blockIdx.x == 0 && t == 0) *flag = f;   // publish for k_main / k_out
    if (f) proj_body<true >(x, Wq, bq, Wk, bk, Wv, bv, Wni, bni, Wnj, bnj, We, proj, Bpack, xs);
    else   proj_body<false>(x, Wq, bq, Wk, bk, Wv, bv, Wni, bni, Wnj, bnj, We, proj, Bpack, xs);
}

// ---------------- K2: main pass --------------------------------------------
template<bool F32>
static __device__ __forceinline__ short8 load_afrag(const void* __restrict__ e, long elem) {
    if (!F32) {
        return ((const short8* __restrict__)e)[elem >> 3];
    } else {
        const float4* __restrict__ p = (const float4* __restrict__)((const float*)e + elem);
        const float4 a = p[0], b = p[1];
        short8 r;
        r[0] = f2bf(a.x); r[1] = f2bf(a.y); r[2] = f2bf(a.z); r[3] = f2bf(a.w);
        r[4] = f2bf(b.x); r[5] = f2bf(b.y); r[6] = f2bf(b.z); r[7] = f2bf(b.w);
        return r;
    }
}

template<bool F32>
static __device__ __forceinline__ void main_body(
    const void* __restrict__ e, const unsigned short* __restrict__ Bpack,
    const void* __restrict__ be, const float* __restrict__ proj,
    float* __restrict__ att, void* __restrict__ d_out)
{
    const int lane = threadIdx.x & 63;
    const int tile = (blockIdx.x << 2) + (threadIdx.x >> 6);   // 0..16383
    const int b   = tile >> 13;            // 8192 tiles per batch
    const int rem = tile & 8191;
    const int i   = rem >> 4;
    const int j0  = (rem & 15) << 5;       // 32-j tile

    const short8* __restrict__ bp = (const short8*)Bpack;
    short8 bfrag[8];
    #pragma unroll
    for (int kk = 0; kk < 8; ++kk) bfrag[kk] = bp[kk * 64 + lane];

    const int m = lane & 15;
    const int g = lane >> 4;
    const long abase = ((long)(b * NN + i) * NN + j0 + m) * DD + g * 8;

    floatx4 acc0 = {0.f, 0.f, 0.f, 0.f};
    floatx4 acc1 = {0.f, 0.f, 0.f, 0.f};
    #pragma unroll
    for (int kk = 0; kk < 8; ++kk) {
        short8 af = load_afrag<F32>(e, abase + kk * 32);
        acc0 = __builtin_amdgcn_mfma_f32_16x16x32_bf16(af, bfrag[kk], acc0, 0, 0, 0);
    }
    #pragma unroll
    for (int kk = 0; kk < 8; ++kk) {
        short8 af = load_afrag<F32>(e, abase + (long)16 * DD + kk * 32);
        acc1 = __builtin_amdgcn_mfma_f32_16x16x32_bf16(af, bfrag[kk], acc1, 0, 0, 0);
    }

    // C/D layout: col(h) = lane&15, row = g*4 + r
    const int h  = m;
    const int bi = b * NN + i;
    const float bev = ldin<F32>(be, h);
    const float Qv  = proj[(0 * (BB * NN) + bi) * DHH + h];
    const float Niv = proj[(3 * (BB * NN) + bi) * DHH + h];
    unsigned short* __restrict__ enew16 = (unsigned short*)d_out + BB * NN * DHH;
    float* __restrict__ enewf = (float*)d_out + BB * NN * DHH;

    #pragma unroll
    for (int sub = 0; sub < 2; ++sub) {
        const floatx4 acc = sub ? acc1 : acc0;
        const int jb = j0 + (sub << 4);
        float scr[4];
        #pragma unroll
        for (int r = 0; r < 4; ++r) {
            const int j  = jb + g * 4 + r;
            const int bj = b * NN + j;
            const float Kv  = proj[(1 * (BB * NN) + bj) * DHH + h];
            const float Njv = proj[(4 * (BB * NN) + bj) * DHH + h];
            const float ev = acc[r] + bev + Niv + Njv;
            const long oidx = ((long)bi * NN + j) * DHH + h;
            if (F32) enewf[oidx] = ev; else enew16[oidx] = f2bf(ev);
            float tv = Qv * ev * Kv;
            tv += __shfl_xor(tv, 1);
            tv += __shfl_xor(tv, 2);
            tv += __shfl_xor(tv, 4);
            tv += __shfl_xor(tv, 8);
            scr[r] = tv;
        }
        if (h < 4) {
            const float sv = (h == 0) ? scr[0] : (h == 1) ? scr[1] : (h == 2) ? scr[2] : scr[3];
            att[(long)bi * NN + (jb + g * 4 + h)] = sv * 0.25f;   // / sqrt(16)
        }
    }
}

__global__ __launch_bounds__(256) void k_main(
    const void* e, const unsigned short* Bpack, const void* be,
    const float* proj, float* att, void* d_out, const int* flag)
{
    if (*flag) main_body<true >(e, Bpack, be, proj, att, d_out);
    else       main_body<false>(e, Bpack, be, proj, att, d_out);
}

// ---------------- K3a: per-(b,j) softmax stats over i ----------------------
__global__ __launch_bounds__(256) void k_colstats(
    const float* __restrict__ att, float* __restrict__ cm, float* __restrict__ cz)
{
    const int lane = threadIdx.x & 63;
    const int col  = (blockIdx.x << 2) + (threadIdx.x >> 6);  // 0..1023 = b*512+j
    const int b = col >> 9;
    const int j = col & 511;
    const float* __restrict__ base = att + (long)b * NN * NN + j;
    float v[8];
    #pragma unroll
    for (int t = 0; t < 8; ++t) v[t] = base[(long)(lane + (t << 6)) * NN];
    float mx = v[0];
    #pragma unroll
    for (int t = 1; t < 8; ++t) mx = fmaxf(mx, v[t]);
    #pragma unroll
    for (int s = 1; s < 64; s <<= 1) mx = fmaxf(mx, __shfl_xor(mx, s));
    float z = 0.f;
    #pragma unroll
    for (int t = 0; t < 8; ++t) z += __expf(v[t] - mx);
    #pragma unroll
    for (int s = 1; s < 64; s <<= 1) z += __shfl_xor(z, s);
    if (lane == 0) { cm[col] = mx; cz[col] = 1.f / z; }
}

// ---------------- K3b: out[b,i,h] = sum_j softmaxed(Att) * V ---------------
template<bool F32>
static __device__ __forceinline__ void out_body(
    const float* __restrict__ att, const float* __restrict__ cm,
    const float* __restrict__ cz, const float* __restrict__ proj,
    void* __restrict__ d_out, float* __restrict__ pls, float* __restrict__ red)
{
    const int bi = blockIdx.x;           // b*512 + i
    const int b  = bi >> 9;
    const int t  = threadIdx.x;
    #pragma unroll
    for (int q = 0; q < 2; ++q) {
        const int j = t + (q << 8);
        const float s = att[(long)bi * NN + j];
        pls[j] = __expf(s - cm[(b << 9) + j]) * cz[(b << 9) + j];
    }
    __syncthreads();
    const int h = t & 15, jg = t >> 4;
    const float* __restrict__ V = proj + (2 * (BB * NN)) * DHH + (long)(b << 9) * DHH;
    float acc = 0.f;
    #pragma unroll 4
    for (int tt = 0; tt < 32; ++tt) {
        const int j = jg * 32 + tt;
        acc += pls[j] * V[j * DHH + h];
    }
    red[t] = acc;
    __syncthreads();
    for (int s = 8; s >= 1; s >>= 1) {
        if (jg < s) red[jg * 16 + h] += red[(jg + s) * 16 + h];
        __syncthreads();
    }
    if (jg == 0) {
        if (F32) ((float*)d_out)[(long)bi * DHH + h] = red[h];
        else     ((unsigned short*)d_out)[(long)bi * DHH + h] = f2bf(red[h]);
    }
}

__global__ __launch_bounds__(256) void k_out(
    const float* att, const float* cm, const float* cz,
    const float* proj, void* d_out, const int* flag)
{
    __shared__ float pls[NN];
    __shared__ float red[256];
    if (*flag) out_body<true >(att, cm, cz, proj, d_out, pls, red);
    else       out_body<false>(att, cm, cz, proj, d_out, pls, red);
}

// ---------------- launch ---------------------------------------------------
extern "C" void kernel_launch(void* const* d_in, const int* in_sizes, int n_in,
                              void* d_out, int out_size, void* d_ws, size_t ws_size,
                              hipStream_t stream)
{
    const void* x   = d_in[0];
    const void* e   = d_in[1];
    const void* Wq  = d_in[2];
    const void* bq  = d_in[3];
    const void* Wk  = d_in[4];
    const void* bk  = d_in[5];
    const void* We  = d_in[6];
    const void* be  = d_in[7];
    const void* Wv  = d_in[8];
    const void* bv  = d_in[9];
    const void* Wni = d_in[10];
    const void* bni = d_in[11];
    const void* Wnj = d_in[12];
    const void* bnj = d_in[13];

    // ws layout (bytes):
    //   proj : 0       .. 327680    (5*1024*16 fp32)
    //   att  : 327680  .. 2424832   (2*512*512 fp32)
    //   cm   : 2424832 .. 2428928   (1024 fp32)
    //   cz   : 2428928 .. 2433024   (1024 fp32)
    //   Bpack: 2433024 .. 2441216   (4096 bf16)
    //   flag : 2441216 .. 2441220   (int)
    char* ws = (char*)d_ws;
    float* proj = (float*)ws;
    float* att  = (float*)(ws + 327680);
    float* cm   = (float*)(ws + 2424832);
    float* cz   = (float*)(ws + 2428928);
    unsigned short* Bpack = (unsigned short*)(ws + 2433024);
    int* flag = (int*)(ws + 2441216);

    k_proj<<<BB * NN, 256, 0, stream>>>(x, Wq, bq, Wk, bk, Wv, bv,
                                        Wni, bni, Wnj, bnj, We, proj, Bpack, flag);
    k_main<<<4096, 256, 0, stream>>>(e, Bpack, be, proj, att, d_out, flag);
    k_colstats<<<256, 256, 0, stream>>>(att, cm, cz);
    k_out<<<BB * NN, 256, 0, stream>>>(att, cm, cz, proj, d_out, flag);
}